// Round 3
// baseline (198.539 us; speedup 1.0000x reference)
//
#include <hip/hip_runtime.h>
#include <hip/hip_bf16.h>
#include <math.h>

typedef unsigned short u16;
typedef float  f32x4  __attribute__((ext_vector_type(4)));
typedef __bf16 bf16x8 __attribute__((ext_vector_type(8)));

#define NPOS   4000
#define LDP    136       // padded bf16 row stride
#define TILE_CH 2176     // 128*136*2/16 16-byte chunks per 128-row tile
#define MSE_N  4194304
#define GATHER_B 256
#define MSE_B    512
#define TLD    132       // f32 voxel-tile row stride (pad, keeps 16B align)

__device__ __forceinline__ void load_lds16(const void* g, void* l) {
  __builtin_amdgcn_global_load_lds(
      (const __attribute__((address_space(1))) unsigned int*)g,
      (__attribute__((address_space(3))) unsigned int*)l, 16, 0, 0);
}

__device__ __forceinline__ float bf2f(u16 h) {
  unsigned u = ((unsigned)h) << 16;
  return __builtin_bit_cast(float, u);
}

struct Args {
  const float* Zs; const int* pos; const int* neg;
  const float4* fd; const float4* idf;
  u16* Pc; u16* Prow; float* Gpart; float* Spart; u16* Gb; float* S;
  float* qpos; float* qneg; float* sdpos; float* sdneg;
  float* msepart; unsigned* qcnt; unsigned* bar; unsigned* gen; float* out;
};

// device-scope arrive/spin grid barrier (all blocks co-resident: 128 <= 256 CUs)
__device__ __forceinline__ void gridbar(unsigned* bar, unsigned* gen, unsigned nb) {
  __syncthreads();
  __threadfence();
  if (threadIdx.x == 0) {
    unsigned g = __hip_atomic_load(gen, __ATOMIC_RELAXED, __HIP_MEMORY_SCOPE_AGENT);
    unsigned prev = __hip_atomic_fetch_add(bar, 1u, __ATOMIC_ACQ_REL, __HIP_MEMORY_SCOPE_AGENT);
    if (prev == nb - 1u) {
      __hip_atomic_store(bar, 0u, __ATOMIC_RELAXED, __HIP_MEMORY_SCOPE_AGENT);
      __hip_atomic_fetch_add(gen, 1u, __ATOMIC_RELEASE, __HIP_MEMORY_SCOPE_AGENT);
    } else {
      while (__hip_atomic_load(gen, __ATOMIC_ACQUIRE, __HIP_MEMORY_SCOPE_AGENT) == g) {
        __builtin_amdgcn_s_sleep(2);
      }
    }
  }
  __syncthreads();
  __threadfence();
}

// ===== kernel 1 (R1-proven): gather + MSE partials + pad zero + counter zero =====
__global__ __launch_bounds__(256) void prep_k(Args a) {
  __shared__ __align__(16) float tile[128 * TLD];   // 67,584 B
  __shared__ int mlist[1024];
  __shared__ int mcnt;
  int blk = blockIdx.x, tid = threadIdx.x;
  int wave = tid >> 6, lane = tid & 63;
  if (blk < GATHER_B) {
    int v0 = blk << 7;
    if (tid == 0) mcnt = 0;
    __syncthreads();
    // stage Zs[:, v0:v0+128] coalesced (float4)
    {
      int rq = tid >> 5;              // 0..7
      int c4 = (tid & 31) << 2;       // 0,4,...,124
      #pragma unroll
      for (int p = 0; p < 16; ++p) {
        int f = p * 8 + rq;
        float4 v = *(const float4*)(a.Zs + ((size_t)f << 15) + v0 + c4);
        *(float4*)&tile[f * TLD + c4] = v;
      }
    }
    // scan indices, build match list (col<<7 | local voxel)
    for (int k = 0; k < 4000; k += 256) {
      int i = k + tid;
      if (i < 4000) {
        unsigned dp = (unsigned)(a.pos[i] - v0);
        if (dp < 128u) { int m = atomicAdd(&mcnt, 1); mlist[m] = (i << 7) | dp; }
        unsigned dn = (unsigned)(a.neg[i] - v0);
        if (dn < 128u) { int m = atomicAdd(&mcnt, 1); mlist[m] = ((4096 + i) << 7) | dn; }
      }
    }
    __syncthreads();
    int nm = mcnt;
    for (int m = wave; m < nm; m += 4) {
      int e = mlist[m];
      int col = e >> 7, lv = e & 127;
      float x0 = tile[lane * TLD + lv];
      float x1 = tile[(lane + 64) * TLD + lv];
      float s = x0 * x0 + x1 * x1;
      #pragma unroll
      for (int o = 1; o < 64; o <<= 1) s += __shfl_xor(s, o, 64);
      float inv = 1.0f / fmaxf(sqrtf(s), 1e-12f);
      __hip_bfloat16 h0 = __float2bfloat16(x0 * inv);
      __hip_bfloat16 h1 = __float2bfloat16(x1 * inv);
      u16 b0 = *(u16*)&h0, b1 = *(u16*)&h1;
      a.Prow[(size_t)col * LDP + lane]      = b0;
      a.Prow[(size_t)col * LDP + lane + 64] = b1;
      size_t cbase = (size_t)(col >> 7) * (128 * LDP) + (col & 127);
      a.Pc[cbase + (size_t)lane * LDP]        = b0;
      a.Pc[cbase + (size_t)(lane + 64) * LDP] = b1;
    }
  } else if (blk < GATHER_B + MSE_B) {
    int b = blk - GATHER_B;
    float ms = 0.f;
    for (int idx = b * 256 + tid; idx < MSE_N / 4; idx += MSE_B * 256) {
      float4 u = a.fd[idx], w = a.idf[idx];
      float dx = u.x - w.x, dy = u.y - w.y, dz = u.z - w.z, dv = u.w - w.w;
      ms += dx * dx + dy * dy + dz * dz + dv * dv;
    }
    #pragma unroll
    for (int o = 1; o < 64; o <<= 1) ms += __shfl_xor(ms, o, 64);
    __shared__ float red[4];
    if (lane == 0) red[wave] = ms;
    __syncthreads();
    if (tid == 0) a.msepart[b] = red[0] + red[1] + red[2] + red[3];
  } else {
    // zero invalid Pc sample columns (chunk 31 & 63, cols 32..127) + sync vars
    int ch = (blk == GATHER_B + MSE_B) ? 31 : 63;
    if (blk == GATHER_B + MSE_B && tid == 0) {
      *a.qcnt = 0u; *a.bar = 0u; *a.gen = 0u;   // ws is poisoned each iter
    }
    for (int e = tid; e < 128 * 96; e += 256) {
      int f = e / 96, c = 32 + e % 96;
      a.Pc[(size_t)ch * (128 * LDP) + (size_t)f * LDP + c] = 0;
    }
  }
}

// ===== kernel 2: mega — syrk | reduce | quad | final, grid-barriered =====
__global__ __launch_bounds__(256) void mega_k(Args a) {
  __shared__ __align__(16) u16 T0[128 * LDP];   // syrk Pc tile, then G tile
  __shared__ __align__(16) u16 T1[128 * LDP];   // quad P tile (preloaded)
  __shared__ float Sl[256];
  __shared__ float qld[2][128];
  int blk = blockIdx.x, tid = threadIdx.x;
  int wave = tid >> 6, lane = tid & 63;
  int cb = blk & 63, set = blk >> 6;
  int wm = (wave >> 1) << 6, wn = (wave & 1) << 6;
  int r = lane & 15, q = lane >> 4;

  // preload quad P tile into T1 (depends only on prep_k) — hides under syrk
  {
    const u16* gP = a.Prow + (size_t)cb * (128 * LDP);
    #pragma unroll
    for (int k = 0; k < 9; ++k) {
      int cc = k * 256 + tid;
      if (cc < TILE_CH) load_lds16(gP + cc * 8, &T1[cc * 8]);
    }
  }

  f32x4 acc[4][4];
  // ---- phase B: SYRK partials on blocks 0..63 ----
  if (blk < 64) {
    #pragma unroll
    for (int x = 0; x < 4; ++x)
      #pragma unroll
      for (int y = 0; y < 4; ++y) {
        acc[x][y][0] = 0.f; acc[x][y][1] = 0.f; acc[x][y][2] = 0.f; acc[x][y][3] = 0.f;
      }
    const u16* g = a.Pc + (size_t)blk * (128 * LDP);
    #pragma unroll
    for (int k = 0; k < 9; ++k) {
      int cc = k * 256 + tid;
      if (cc < TILE_CH) load_lds16(g + cc * 8, &T0[cc * 8]);
    }
    __syncthreads();
    #pragma unroll
    for (int kk = 0; kk < 4; ++kk) {
      int k0 = kk * 32 + q * 8;
      bf16x8 af[4], bfr[4];
      #pragma unroll
      for (int t = 0; t < 4; ++t) {
        af[t]  = *(const bf16x8*)&T0[(wm + t * 16 + r) * LDP + k0];
        bfr[t] = *(const bf16x8*)&T0[(wn + t * 16 + r) * LDP + k0];
      }
      #pragma unroll
      for (int mt = 0; mt < 4; ++mt)
        #pragma unroll
        for (int nt = 0; nt < 4; ++nt)
          acc[mt][nt] = __builtin_amdgcn_mfma_f32_16x16x32_bf16(
              af[mt], bfr[nt], acc[mt][nt], 0, 0, 0);
    }
    // per-tile column (feature) sums -> S partials
    {
      int sf = tid >> 1, sh = tid & 1;
      float ssum = 0.f;
      const u16* base = &T0[sf * LDP + sh * 64];
      #pragma unroll
      for (int vb = 0; vb < 8; ++vb) {
        bf16x8 v = *(const bf16x8*)&base[vb * 8];
        #pragma unroll
        for (int j = 0; j < 8; ++j) ssum += (float)v[j];
      }
      ssum += __shfl_xor(ssum, 1, 64);
      if (sh == 0) a.Spart[blk * 128 + sf] = ssum;
    }
    // plain coalesced partial store
    float* Gp = a.Gpart + (size_t)blk * 16384;
    #pragma unroll
    for (int mt = 0; mt < 4; ++mt)
      #pragma unroll
      for (int nt = 0; nt < 4; ++nt)
        #pragma unroll
        for (int reg = 0; reg < 4; ++reg) {
          int ar = wm + mt * 16 + q * 4 + reg;
          int bc = wn + nt * 16 + r;
          Gp[ar * 128 + bc] = acc[mt][nt][reg];
        }
  }
  gridbar(a.bar, a.gen, 128u);

  // ---- phase C: reduce partials -> Gb (bf16 padded) + S ----
  if (blk < 64) {
    int set_r = blk >> 5, f0 = (blk & 31) * 4;
    #pragma unroll
    for (int j = 0; j < 2; ++j) {
      int o = j * 256 + tid;                 // 0..511
      int row = f0 + (o >> 7), col = o & 127;
      const float* src = a.Gpart + (size_t)set_r * 32 * 16384 + row * 128 + col;
      float s = 0.f;
      #pragma unroll
      for (int ch = 0; ch < 32; ++ch) s += src[(size_t)ch * 16384];
      __hip_bfloat16 h = __float2bfloat16(s);
      a.Gb[(size_t)set_r * (128 * LDP) + row * LDP + col] = *(u16*)&h;
    }
  } else if (blk == 64) {
    int set_r = tid >> 7, f = tid & 127;
    const float* sp = a.Spart + (size_t)set_r * 32 * 128 + f;
    float s = 0.f;
    #pragma unroll
    for (int ch = 0; ch < 32; ++ch) s += sp[ch * 128];
    a.S[tid] = s;
  }
  gridbar(a.bar, a.gen, 128u);

  // ---- phase D: quadratic forms (all 128 blocks) ----
  {
    const u16* gG = a.Gb + (size_t)set * (128 * LDP);
    #pragma unroll
    for (int k = 0; k < 9; ++k) {
      int cc = k * 256 + tid;
      if (cc < TILE_CH) load_lds16(gG + cc * 8, &T0[cc * 8]);
    }
  }
  Sl[tid] = a.S[tid];
  __syncthreads();
  #pragma unroll
  for (int x = 0; x < 4; ++x)
    #pragma unroll
    for (int y = 0; y < 4; ++y) {
      acc[x][y][0] = 0.f; acc[x][y][1] = 0.f; acc[x][y][2] = 0.f; acc[x][y][3] = 0.f;
    }
  #pragma unroll
  for (int kk = 0; kk < 4; ++kk) {
    int k0 = kk * 32 + q * 8;
    bf16x8 af[4], bfr[4];
    #pragma unroll
    for (int t = 0; t < 4; ++t) {
      af[t]  = *(const bf16x8*)&T0[(wm + t * 16 + r) * LDP + k0];
      bfr[t] = *(const bf16x8*)&T1[(wn + t * 16 + r) * LDP + k0];
    }
    #pragma unroll
    for (int mt = 0; mt < 4; ++mt)
      #pragma unroll
      for (int nt = 0; nt < 4; ++nt)
        acc[mt][nt] = __builtin_amdgcn_mfma_f32_16x16x32_bf16(
            af[mt], bfr[nt], acc[mt][nt], 0, 0, 0);
  }
  float qv[4] = {0.f, 0.f, 0.f, 0.f};
  #pragma unroll
  for (int nt = 0; nt < 4; ++nt) {
    int il = wn + nt * 16 + r;
    #pragma unroll
    for (int mt = 0; mt < 4; ++mt) {
      const u16* pp = &T1[il * LDP + wm + mt * 16 + q * 4];
      #pragma unroll
      for (int reg = 0; reg < 4; ++reg)
        qv[nt] += acc[mt][nt][reg] * bf2f(pp[reg]);
    }
  }
  #pragma unroll
  for (int nt = 0; nt < 4; ++nt) {
    qv[nt] += __shfl_xor(qv[nt], 16, 64);
    qv[nt] += __shfl_xor(qv[nt], 32, 64);
  }
  int half = wm >> 6;
  if (q == 0) {
    #pragma unroll
    for (int nt = 0; nt < 4; ++nt) qld[half][wn + nt * 16 + r] = qv[nt];
  }
  __syncthreads();
  float* qarr = set ? a.qneg : a.qpos;
  if (tid < 128) qarr[cb * 128 + tid] = qld[0][tid] + qld[1][tid];
  if (set == 0) {
    int which = tid >> 7, sl = tid & 127;
    const float* Sv = &Sl[which * 128];
    float d = 0.f;
    #pragma unroll
    for (int fb = 0; fb < 16; ++fb) {
      const u16* pv = &T1[sl * LDP + fb * 8];
      #pragma unroll
      for (int j = 0; j < 8; ++j) d += Sv[fb * 8 + j] * bf2f(pv[j]);
    }
    (which ? a.sdneg : a.sdpos)[cb * 128 + sl] = d;
  }

  // ---- tail-block final combine ----
  __threadfence();
  __syncthreads();
  __shared__ unsigned lastv;
  if (tid == 0) lastv = atomicAdd(a.qcnt, 1u);
  __syncthreads();
  if (lastv != 127u) return;
  __threadfence();
  int wv = tid >> 6, lane2 = tid & 63;
  float lg = 0.f, sm = 0.f;
  for (int col = tid; col < 8192; col += 256) {
    bool isp = col < NPOS;
    bool isn = (col >= 4096) && (col < 4096 + NPOS);
    if (isp || isn) {
      float qp = a.qpos[col], qn = a.qneg[col];
      float c = 1.0f / sqrtf(qp + qn);
      float qo  = isp ? qn : qp;
      float sdo = isp ? a.sdneg[col] : a.sdpos[col];
      float sds = isp ? a.sdpos[col] : a.sdneg[col];
      float denom = 4000.0f + c * sdo + 0.5f * c * c * qo;
      lg += logf(denom);
      sm += c * (sds - 1.0f);
    }
  }
  float ms = a.msepart[tid] + a.msepart[tid + 256];
  #pragma unroll
  for (int o = 1; o < 64; o <<= 1) {
    lg += __shfl_xor(lg, o, 64);
    sm += __shfl_xor(sm, o, 64);
    ms += __shfl_xor(ms, o, 64);
  }
  __shared__ float redf[12];
  if (lane2 == 0) { redf[wv] = lg; redf[4 + wv] = sm; redf[8 + wv] = ms; }
  __syncthreads();
  if (tid == 0) {
    float lgs = redf[0] + redf[1] + redf[2] + redf[3];
    float sms = redf[4] + redf[5] + redf[6] + redf[7];
    float mss = redf[8] + redf[9] + redf[10] + redf[11];
    a.out[0] = lgs - sms * (1.0f / 8000.0f) + 0.5f * (mss * (1.0f / (float)MSE_N));
  }
}

extern "C" void kernel_launch(void* const* d_in, const int* in_sizes, int n_in,
                              void* d_out, int out_size, void* d_ws, size_t ws_size,
                              hipStream_t stream) {
  char* ws = (char*)d_ws;
  Args args;
  args.Zs  = (const float*)d_in[0];
  args.pos = (const int*)d_in[1];
  args.neg = (const int*)d_in[2];
  args.fd  = (const float4*)d_in[3];
  args.idf = (const float4*)d_in[4];
  args.out = (float*)d_out;

  args.Pc      = (u16*)(ws + 0);            // 2,228,224 B
  args.Prow    = (u16*)(ws + 2228224);      // -> 4,456,448
  args.Gpart   = (float*)(ws + 4456448);    // 4,194,304 -> 8,650,752
  args.Spart   = (float*)(ws + 8650752);    //    32,768 -> 8,683,520
  args.Gb      = (u16*)(ws + 8683520);      //    69,632 -> 8,753,152
  args.S       = (float*)(ws + 8753152);    //     1,024 -> 8,754,176
  args.qpos    = (float*)(ws + 8754176);    //    32,768 -> 8,786,944
  args.qneg    = (float*)(ws + 8786944);    //    32,768 -> 8,819,712
  args.sdpos   = (float*)(ws + 8819712);    //    32,768 -> 8,852,480
  args.sdneg   = (float*)(ws + 8852480);    //    32,768 -> 8,885,248
  args.msepart = (float*)(ws + 8885248);    //     2,048 -> 8,887,296
  args.qcnt    = (unsigned*)(ws + 8887296); //         4 -> 8,887,300
  args.bar     = (unsigned*)(ws + 8887300); //         4 -> 8,887,304
  args.gen     = (unsigned*)(ws + 8887304); //         4 -> 8,887,308

  prep_k<<<GATHER_B + MSE_B + 2, 256, 0, stream>>>(args);
  mega_k<<<128, 256, 0, stream>>>(args);
}

// Round 5
// 140.538 us; speedup vs baseline: 1.4127x; 1.4127x over previous
//
#include <hip/hip_runtime.h>
#include <hip/hip_bf16.h>
#include <math.h>

typedef unsigned short u16;
typedef float  f32x4  __attribute__((ext_vector_type(4)));
typedef __bf16 bf16x8 __attribute__((ext_vector_type(8)));

#define NPOS   4000
#define LDP    136       // padded bf16 row stride
#define TILE_CH 2176     // 128*136*2/16 16-byte chunks per 128-row tile
#define MSE_N  4194304
#define GATHER_B 256
#define MSE_B    512
#define TLD    132       // f32 voxel-tile row stride (pad, keeps 16B align)

__device__ __forceinline__ void load_lds16(const void* g, void* l) {
  __builtin_amdgcn_global_load_lds(
      (const __attribute__((address_space(1))) unsigned int*)g,
      (__attribute__((address_space(3))) unsigned int*)l, 16, 0, 0);
}

__device__ __forceinline__ float bf2f(u16 h) {
  unsigned u = ((unsigned)h) << 16;
  return __builtin_bit_cast(float, u);
}

struct Args {
  const float* Zs; const int* pos; const int* neg;
  const float4* fd; const float4* idf;
  u16* Pc; u16* Prow; u16* Gb; float* S;
  float* qpos; float* qneg; float* sdpos; float* sdneg;
  float* msepart; unsigned* qcnt; float* out;
};

// ===== kernel 1 (R1-proven): gather + MSE partials + pad zero + counter zero =====
__global__ __launch_bounds__(256) void prep_k(Args a) {
  __shared__ __align__(16) float tile[128 * TLD];   // 67,584 B
  __shared__ int mlist[1024];
  __shared__ int mcnt;
  int blk = blockIdx.x, tid = threadIdx.x;
  int wave = tid >> 6, lane = tid & 63;
  if (blk < GATHER_B) {
    int v0 = blk << 7;
    if (tid == 0) mcnt = 0;
    __syncthreads();
    // stage Zs[:, v0:v0+128] coalesced (float4)
    {
      int rq = tid >> 5;              // 0..7
      int c4 = (tid & 31) << 2;       // 0,4,...,124
      #pragma unroll
      for (int p = 0; p < 16; ++p) {
        int f = p * 8 + rq;
        float4 v = *(const float4*)(a.Zs + ((size_t)f << 15) + v0 + c4);
        *(float4*)&tile[f * TLD + c4] = v;
      }
    }
    // scan indices, build match list (col<<7 | local voxel)
    for (int k = 0; k < 4000; k += 256) {
      int i = k + tid;
      if (i < 4000) {
        unsigned dp = (unsigned)(a.pos[i] - v0);
        if (dp < 128u) { int m = atomicAdd(&mcnt, 1); mlist[m] = (i << 7) | dp; }
        unsigned dn = (unsigned)(a.neg[i] - v0);
        if (dn < 128u) { int m = atomicAdd(&mcnt, 1); mlist[m] = ((4096 + i) << 7) | dn; }
      }
    }
    __syncthreads();
    int nm = mcnt;
    for (int m = wave; m < nm; m += 4) {
      int e = mlist[m];
      int col = e >> 7, lv = e & 127;
      float x0 = tile[lane * TLD + lv];
      float x1 = tile[(lane + 64) * TLD + lv];
      float s = x0 * x0 + x1 * x1;
      #pragma unroll
      for (int o = 1; o < 64; o <<= 1) s += __shfl_xor(s, o, 64);
      float inv = 1.0f / fmaxf(sqrtf(s), 1e-12f);
      __hip_bfloat16 h0 = __float2bfloat16(x0 * inv);
      __hip_bfloat16 h1 = __float2bfloat16(x1 * inv);
      u16 b0 = *(u16*)&h0, b1 = *(u16*)&h1;
      a.Prow[(size_t)col * LDP + lane]      = b0;
      a.Prow[(size_t)col * LDP + lane + 64] = b1;
      size_t cbase = (size_t)(col >> 7) * (128 * LDP) + (col & 127);
      a.Pc[cbase + (size_t)lane * LDP]        = b0;
      a.Pc[cbase + (size_t)(lane + 64) * LDP] = b1;
    }
  } else if (blk < GATHER_B + MSE_B) {
    int b = blk - GATHER_B;
    float ms = 0.f;
    for (int idx = b * 256 + tid; idx < MSE_N / 4; idx += MSE_B * 256) {
      float4 u = a.fd[idx], w = a.idf[idx];
      float dx = u.x - w.x, dy = u.y - w.y, dz = u.z - w.z, dv = u.w - w.w;
      ms += dx * dx + dy * dy + dz * dz + dv * dv;
    }
    #pragma unroll
    for (int o = 1; o < 64; o <<= 1) ms += __shfl_xor(ms, o, 64);
    __shared__ float red[4];
    if (lane == 0) red[wave] = ms;
    __syncthreads();
    if (tid == 0) a.msepart[b] = red[0] + red[1] + red[2] + red[3];
  } else {
    // zero invalid Pc sample columns (chunk 31 & 63, cols 32..127) + counter
    int ch = (blk == GATHER_B + MSE_B) ? 31 : 63;
    if (blk == GATHER_B + MSE_B && tid == 0) *a.qcnt = 0u;   // ws poisoned each iter
    for (int e = tid; e < 128 * 96; e += 256) {
      int f = e / 96, c = 32 + e % 96;
      a.Pc[(size_t)ch * (128 * LDP) + (size_t)f * LDP + c] = 0;
    }
  }
}

// ===== kernel 2: direct-G SYRK — 128 blocks, one 16x16 G-tile each, no partials =====
// block b: set = b>>6; (fi,fj) = 16x16 tile of G_set. 4 waves split the 32
// sample-tiles (K=4096) and accumulate in MFMA; 4KB LDS cross-wave reduce.
// Diagonal blocks also emit S (column sums) from their A-fragments for free.
__global__ __launch_bounds__(256) void gsyrk_k(Args a) {
  __shared__ float red[4][256];
  __shared__ float sred[4][16];
  int blk = blockIdx.x, tid = threadIdx.x;
  int wave = tid >> 6, lane = tid & 63;
  int set = blk >> 6, t64 = blk & 63;
  int fi = (t64 >> 3) << 4, fj = (t64 & 7) << 4;
  int r = lane & 15, q = lane >> 4;
  const u16* base = a.Pc + (size_t)set * 32 * (128 * LDP);
  f32x4 acc = {0.f, 0.f, 0.f, 0.f};
  float ssum = 0.f;
  const bool diag = (fi == fj);
  for (int t = wave; t < 32; t += 4) {
    const u16* tp = base + (size_t)t * (128 * LDP);
    #pragma unroll
    for (int kk = 0; kk < 4; ++kk) {
      int k0 = kk * 32 + q * 8;
      bf16x8 af  = *(const bf16x8*)&tp[(fi + r) * LDP + k0];
      bf16x8 bfr = *(const bf16x8*)&tp[(fj + r) * LDP + k0];
      acc = __builtin_amdgcn_mfma_f32_16x16x32_bf16(af, bfr, acc, 0, 0, 0);
      if (diag) {
        #pragma unroll
        for (int j = 0; j < 8; ++j) ssum += (float)af[j];
      }
    }
  }
  #pragma unroll
  for (int g2 = 0; g2 < 4; ++g2) red[wave][lane * 4 + g2] = acc[g2];
  if (diag) {
    ssum += __shfl_xor(ssum, 16, 64);   // sum over q bit0
    ssum += __shfl_xor(ssum, 32, 64);   // sum over q bit1
    if (q == 0) sred[wave][r] = ssum;
  }
  __syncthreads();
  if (wave == 0) {
    #pragma unroll
    for (int g2 = 0; g2 < 4; ++g2) {
      float v = red[0][lane * 4 + g2] + red[1][lane * 4 + g2]
              + red[2][lane * 4 + g2] + red[3][lane * 4 + g2];
      __hip_bfloat16 h = __float2bfloat16(v);
      a.Gb[(size_t)set * (128 * LDP) + (size_t)(fi + q * 4 + g2) * LDP + (fj + r)] = *(u16*)&h;
    }
    if (diag && lane < 16)
      a.S[set * 128 + fi + lane] =
          sred[0][lane] + sred[1][lane] + sred[2][lane] + sred[3][lane];
  }
}

// ===== kernel 3: quadratic forms + S-dots; LAST block does final combine =====
__global__ __launch_bounds__(256) void quad_k(Args a) {
  __shared__ __align__(16) u16 T0[128 * LDP];   // G in bf16
  __shared__ __align__(16) u16 T1[128 * LDP];   // P tile
  __shared__ float Sl[256];
  __shared__ float qld[2][128];
  int cb = blockIdx.x & 63, set = blockIdx.x >> 6, tid = threadIdx.x;
  Sl[tid] = a.S[tid];
  const u16* gP = a.Prow + (size_t)cb * (128 * LDP);
  #pragma unroll
  for (int k = 0; k < 9; ++k) {
    int cc = k * 256 + tid;
    if (cc < TILE_CH) load_lds16(gP + cc * 8, &T1[cc * 8]);
  }
  const u16* gG = a.Gb + (size_t)set * (128 * LDP);
  #pragma unroll
  for (int k = 0; k < 9; ++k) {
    int cc = k * 256 + tid;
    if (cc < TILE_CH) load_lds16(gG + cc * 8, &T0[cc * 8]);
  }
  __syncthreads();
  int wave = tid >> 6, lane = tid & 63;
  int wm = (wave >> 1) << 6, wn = (wave & 1) << 6;
  int r = lane & 15, q = lane >> 4;
  f32x4 acc[4][4];
  #pragma unroll
  for (int x = 0; x < 4; ++x)
    #pragma unroll
    for (int y = 0; y < 4; ++y) {
      acc[x][y][0] = 0.f; acc[x][y][1] = 0.f; acc[x][y][2] = 0.f; acc[x][y][3] = 0.f;
    }
  #pragma unroll
  for (int kk = 0; kk < 4; ++kk) {
    int k0 = kk * 32 + q * 8;
    bf16x8 af[4], bfr[4];
    #pragma unroll
    for (int t = 0; t < 4; ++t) {
      af[t]  = *(const bf16x8*)&T0[(wm + t * 16 + r) * LDP + k0];
      bfr[t] = *(const bf16x8*)&T1[(wn + t * 16 + r) * LDP + k0];
    }
    #pragma unroll
    for (int mt = 0; mt < 4; ++mt)
      #pragma unroll
      for (int nt = 0; nt < 4; ++nt)
        acc[mt][nt] = __builtin_amdgcn_mfma_f32_16x16x32_bf16(
            af[mt], bfr[nt], acc[mt][nt], 0, 0, 0);
  }
  float qv[4] = {0.f, 0.f, 0.f, 0.f};
  #pragma unroll
  for (int nt = 0; nt < 4; ++nt) {
    int il = wn + nt * 16 + r;
    #pragma unroll
    for (int mt = 0; mt < 4; ++mt) {
      const u16* pp = &T1[il * LDP + wm + mt * 16 + q * 4];
      #pragma unroll
      for (int reg = 0; reg < 4; ++reg)
        qv[nt] += acc[mt][nt][reg] * bf2f(pp[reg]);
    }
  }
  #pragma unroll
  for (int nt = 0; nt < 4; ++nt) {
    qv[nt] += __shfl_xor(qv[nt], 16, 64);
    qv[nt] += __shfl_xor(qv[nt], 32, 64);
  }
  int half = wm >> 6;
  if (q == 0) {
    #pragma unroll
    for (int nt = 0; nt < 4; ++nt) qld[half][wn + nt * 16 + r] = qv[nt];
  }
  __syncthreads();
  float* qarr = set ? a.qneg : a.qpos;
  if (tid < 128) qarr[cb * 128 + tid] = qld[0][tid] + qld[1][tid];
  if (set == 0) {
    int which = tid >> 7, sl = tid & 127;
    const float* Sv = &Sl[which * 128];
    float d = 0.f;
    #pragma unroll
    for (int fb = 0; fb < 16; ++fb) {
      const u16* pv = &T1[sl * LDP + fb * 8];
      #pragma unroll
      for (int j = 0; j < 8; ++j) d += Sv[fb * 8 + j] * bf2f(pv[j]);
    }
    (which ? a.sdneg : a.sdpos)[cb * 128 + sl] = d;
  }
  // ---- tail-block final combine (R2-proven pattern; no spinning) ----
  __threadfence();
  __syncthreads();
  __shared__ unsigned lastv;
  if (tid == 0) lastv = atomicAdd(a.qcnt, 1u);
  __syncthreads();
  if (lastv != 127u) return;
  __threadfence();
  int wv = tid >> 6, lane2 = tid & 63;
  float lg = 0.f, sm = 0.f;
  for (int col = tid; col < 8192; col += 256) {
    bool isp = col < NPOS;
    bool isn = (col >= 4096) && (col < 4096 + NPOS);
    if (isp || isn) {
      float qp = a.qpos[col], qn = a.qneg[col];
      float c = 1.0f / sqrtf(qp + qn);
      float qo  = isp ? qn : qp;
      float sdo = isp ? a.sdneg[col] : a.sdpos[col];
      float sds = isp ? a.sdpos[col] : a.sdneg[col];
      float denom = 4000.0f + c * sdo + 0.5f * c * c * qo;
      lg += logf(denom);
      sm += c * (sds - 1.0f);
    }
  }
  float ms = a.msepart[tid] + a.msepart[tid + 256];
  #pragma unroll
  for (int o = 1; o < 64; o <<= 1) {
    lg += __shfl_xor(lg, o, 64);
    sm += __shfl_xor(sm, o, 64);
    ms += __shfl_xor(ms, o, 64);
  }
  __shared__ float redf[12];
  if (lane2 == 0) { redf[wv] = lg; redf[4 + wv] = sm; redf[8 + wv] = ms; }
  __syncthreads();
  if (tid == 0) {
    float lgs = redf[0] + redf[1] + redf[2] + redf[3];
    float sms = redf[4] + redf[5] + redf[6] + redf[7];
    float mss = redf[8] + redf[9] + redf[10] + redf[11];
    a.out[0] = lgs - sms * (1.0f / 8000.0f) + 0.5f * (mss * (1.0f / (float)MSE_N));
  }
}

extern "C" void kernel_launch(void* const* d_in, const int* in_sizes, int n_in,
                              void* d_out, int out_size, void* d_ws, size_t ws_size,
                              hipStream_t stream) {
  char* ws = (char*)d_ws;
  Args args;
  args.Zs  = (const float*)d_in[0];
  args.pos = (const int*)d_in[1];
  args.neg = (const int*)d_in[2];
  args.fd  = (const float4*)d_in[3];
  args.idf = (const float4*)d_in[4];
  args.out = (float*)d_out;

  args.Pc      = (u16*)(ws + 0);            // 2,228,224 B
  args.Prow    = (u16*)(ws + 2228224);      // -> 4,456,448
  args.Gb      = (u16*)(ws + 4456448);      //    69,632 -> 4,526,080
  args.S       = (float*)(ws + 4526080);    //     1,024 -> 4,527,104
  args.qpos    = (float*)(ws + 4527104);    //    32,768 -> 4,559,872
  args.qneg    = (float*)(ws + 4559872);    //    32,768 -> 4,592,640
  args.sdpos   = (float*)(ws + 4592640);    //    32,768 -> 4,625,408
  args.sdneg   = (float*)(ws + 4625408);    //    32,768 -> 4,658,176
  args.msepart = (float*)(ws + 4658176);    //     2,048 -> 4,660,224
  args.qcnt    = (unsigned*)(ws + 4660224); //         4 -> 4,660,228

  prep_k<<<GATHER_B + MSE_B + 2, 256, 0, stream>>>(args);
  gsyrk_k<<<128, 256, 0, stream>>>(args);
  quad_k<<<128, 256, 0, stream>>>(args);
}

// Round 6
// 131.884 us; speedup vs baseline: 1.5054x; 1.0656x over previous
//
#include <hip/hip_runtime.h>
#include <hip/hip_bf16.h>
#include <math.h>

typedef unsigned short u16;
typedef float  f32x4  __attribute__((ext_vector_type(4)));
typedef __bf16 bf16x8 __attribute__((ext_vector_type(8)));

#define NPOS   4000
#define LDP    136       // padded bf16 row stride
#define TILE_CH 2176     // 128*136*2/16 16-byte chunks per 128-row tile
#define MSE_N  4194304
#define GATHER_B 256
#define MSE_B    512
#define TLD    132       // f32 voxel-tile row stride (pad, keeps 16B align)

__device__ __forceinline__ void load_lds16(const void* g, void* l) {
  __builtin_amdgcn_global_load_lds(
      (const __attribute__((address_space(1))) unsigned int*)g,
      (__attribute__((address_space(3))) unsigned int*)l, 16, 0, 0);
}

__device__ __forceinline__ float bf2f(u16 h) {
  unsigned u = ((unsigned)h) << 16;
  return __builtin_bit_cast(float, u);
}

struct Args {
  const float* Zs; const int* pos; const int* neg;
  const float4* fd; const float4* idf;
  u16* Pc; u16* Prow; u16* Gb; float* S;
  float* qpos; float* qneg; float* sdpos; float* sdneg;
  float* msepart; float* out;
};

// ===== kernel 1 (R1-proven): gather + MSE partials + pad zero =====
__global__ __launch_bounds__(256) void prep_k(Args a) {
  __shared__ __align__(16) float tile[128 * TLD];   // 67,584 B
  __shared__ int mlist[1024];
  __shared__ int mcnt;
  int blk = blockIdx.x, tid = threadIdx.x;
  int wave = tid >> 6, lane = tid & 63;
  if (blk < GATHER_B) {
    int v0 = blk << 7;
    if (tid == 0) mcnt = 0;
    __syncthreads();
    // stage Zs[:, v0:v0+128] coalesced (float4)
    {
      int rq = tid >> 5;              // 0..7
      int c4 = (tid & 31) << 2;       // 0,4,...,124
      #pragma unroll
      for (int p = 0; p < 16; ++p) {
        int f = p * 8 + rq;
        float4 v = *(const float4*)(a.Zs + ((size_t)f << 15) + v0 + c4);
        *(float4*)&tile[f * TLD + c4] = v;
      }
    }
    // scan indices, build match list (col<<7 | local voxel)
    for (int k = 0; k < 4000; k += 256) {
      int i = k + tid;
      if (i < 4000) {
        unsigned dp = (unsigned)(a.pos[i] - v0);
        if (dp < 128u) { int m = atomicAdd(&mcnt, 1); mlist[m] = (i << 7) | dp; }
        unsigned dn = (unsigned)(a.neg[i] - v0);
        if (dn < 128u) { int m = atomicAdd(&mcnt, 1); mlist[m] = ((4096 + i) << 7) | dn; }
      }
    }
    __syncthreads();
    int nm = mcnt;
    for (int m = wave; m < nm; m += 4) {
      int e = mlist[m];
      int col = e >> 7, lv = e & 127;
      float x0 = tile[lane * TLD + lv];
      float x1 = tile[(lane + 64) * TLD + lv];
      float s = x0 * x0 + x1 * x1;
      #pragma unroll
      for (int o = 1; o < 64; o <<= 1) s += __shfl_xor(s, o, 64);
      float inv = 1.0f / fmaxf(sqrtf(s), 1e-12f);
      __hip_bfloat16 h0 = __float2bfloat16(x0 * inv);
      __hip_bfloat16 h1 = __float2bfloat16(x1 * inv);
      u16 b0 = *(u16*)&h0, b1 = *(u16*)&h1;
      a.Prow[(size_t)col * LDP + lane]      = b0;
      a.Prow[(size_t)col * LDP + lane + 64] = b1;
      size_t cbase = (size_t)(col >> 7) * (128 * LDP) + (col & 127);
      a.Pc[cbase + (size_t)lane * LDP]        = b0;
      a.Pc[cbase + (size_t)(lane + 64) * LDP] = b1;
    }
  } else if (blk < GATHER_B + MSE_B) {
    int b = blk - GATHER_B;
    float ms = 0.f;
    for (int idx = b * 256 + tid; idx < MSE_N / 4; idx += MSE_B * 256) {
      float4 u = a.fd[idx], w = a.idf[idx];
      float dx = u.x - w.x, dy = u.y - w.y, dz = u.z - w.z, dv = u.w - w.w;
      ms += dx * dx + dy * dy + dz * dz + dv * dv;
    }
    #pragma unroll
    for (int o = 1; o < 64; o <<= 1) ms += __shfl_xor(ms, o, 64);
    __shared__ float red[4];
    if (lane == 0) red[wave] = ms;
    __syncthreads();
    if (tid == 0) a.msepart[b] = red[0] + red[1] + red[2] + red[3];
  } else {
    // zero invalid Pc sample columns (chunk 31 & 63, cols 32..127)
    int ch = (blk == GATHER_B + MSE_B) ? 31 : 63;
    for (int e = tid; e < 128 * 96; e += 256) {
      int f = e / 96, c = 32 + e % 96;
      a.Pc[(size_t)ch * (128 * LDP) + (size_t)f * LDP + c] = 0;
    }
  }
}

// ===== kernel 2: direct-G SYRK — 128 blocks, one 16x16 G-tile each, no partials =====
__global__ __launch_bounds__(256) void gsyrk_k(Args a) {
  __shared__ float red[4][256];
  __shared__ float sred[4][16];
  int blk = blockIdx.x, tid = threadIdx.x;
  int wave = tid >> 6, lane = tid & 63;
  int set = blk >> 6, t64 = blk & 63;
  int fi = (t64 >> 3) << 4, fj = (t64 & 7) << 4;
  int r = lane & 15, q = lane >> 4;
  const u16* base = a.Pc + (size_t)set * 32 * (128 * LDP);
  f32x4 acc = {0.f, 0.f, 0.f, 0.f};
  float ssum = 0.f;
  const bool diag = (fi == fj);
  for (int t = wave; t < 32; t += 4) {
    const u16* tp = base + (size_t)t * (128 * LDP);
    #pragma unroll
    for (int kk = 0; kk < 4; ++kk) {
      int k0 = kk * 32 + q * 8;
      bf16x8 af  = *(const bf16x8*)&tp[(fi + r) * LDP + k0];
      bf16x8 bfr = *(const bf16x8*)&tp[(fj + r) * LDP + k0];
      acc = __builtin_amdgcn_mfma_f32_16x16x32_bf16(af, bfr, acc, 0, 0, 0);
      if (diag) {
        #pragma unroll
        for (int j = 0; j < 8; ++j) ssum += (float)af[j];
      }
    }
  }
  #pragma unroll
  for (int g2 = 0; g2 < 4; ++g2) red[wave][lane * 4 + g2] = acc[g2];
  if (diag) {
    ssum += __shfl_xor(ssum, 16, 64);
    ssum += __shfl_xor(ssum, 32, 64);
    if (q == 0) sred[wave][r] = ssum;
  }
  __syncthreads();
  if (wave == 0) {
    #pragma unroll
    for (int g2 = 0; g2 < 4; ++g2) {
      float v = red[0][lane * 4 + g2] + red[1][lane * 4 + g2]
              + red[2][lane * 4 + g2] + red[3][lane * 4 + g2];
      __hip_bfloat16 h = __float2bfloat16(v);
      a.Gb[(size_t)set * (128 * LDP) + (size_t)(fi + q * 4 + g2) * LDP + (fj + r)] = *(u16*)&h;
    }
    if (diag && lane < 16)
      a.S[set * 128 + fi + lane] =
          sred[0][lane] + sred[1][lane] + sred[2][lane] + sred[3][lane];
  }
}

// ===== kernel 3: quadratic forms + S-dots (no tail fusion) =====
__global__ __launch_bounds__(256) void quad_k(Args a) {
  __shared__ __align__(16) u16 T0[128 * LDP];   // G in bf16
  __shared__ __align__(16) u16 T1[128 * LDP];   // P tile
  __shared__ float Sl[256];
  __shared__ float qld[2][128];
  int cb = blockIdx.x & 63, set = blockIdx.x >> 6, tid = threadIdx.x;
  Sl[tid] = a.S[tid];
  const u16* gP = a.Prow + (size_t)cb * (128 * LDP);
  #pragma unroll
  for (int k = 0; k < 9; ++k) {
    int cc = k * 256 + tid;
    if (cc < TILE_CH) load_lds16(gP + cc * 8, &T1[cc * 8]);
  }
  const u16* gG = a.Gb + (size_t)set * (128 * LDP);
  #pragma unroll
  for (int k = 0; k < 9; ++k) {
    int cc = k * 256 + tid;
    if (cc < TILE_CH) load_lds16(gG + cc * 8, &T0[cc * 8]);
  }
  __syncthreads();
  int wave = tid >> 6, lane = tid & 63;
  int wm = (wave >> 1) << 6, wn = (wave & 1) << 6;
  int r = lane & 15, q = lane >> 4;
  f32x4 acc[4][4];
  #pragma unroll
  for (int x = 0; x < 4; ++x)
    #pragma unroll
    for (int y = 0; y < 4; ++y) {
      acc[x][y][0] = 0.f; acc[x][y][1] = 0.f; acc[x][y][2] = 0.f; acc[x][y][3] = 0.f;
    }
  #pragma unroll
  for (int kk = 0; kk < 4; ++kk) {
    int k0 = kk * 32 + q * 8;
    bf16x8 af[4], bfr[4];
    #pragma unroll
    for (int t = 0; t < 4; ++t) {
      af[t]  = *(const bf16x8*)&T0[(wm + t * 16 + r) * LDP + k0];
      bfr[t] = *(const bf16x8*)&T1[(wn + t * 16 + r) * LDP + k0];
    }
    #pragma unroll
    for (int mt = 0; mt < 4; ++mt)
      #pragma unroll
      for (int nt = 0; nt < 4; ++nt)
        acc[mt][nt] = __builtin_amdgcn_mfma_f32_16x16x32_bf16(
            af[mt], bfr[nt], acc[mt][nt], 0, 0, 0);
  }
  float qv[4] = {0.f, 0.f, 0.f, 0.f};
  #pragma unroll
  for (int nt = 0; nt < 4; ++nt) {
    int il = wn + nt * 16 + r;
    #pragma unroll
    for (int mt = 0; mt < 4; ++mt) {
      const u16* pp = &T1[il * LDP + wm + mt * 16 + q * 4];
      #pragma unroll
      for (int reg = 0; reg < 4; ++reg)
        qv[nt] += acc[mt][nt][reg] * bf2f(pp[reg]);
    }
  }
  #pragma unroll
  for (int nt = 0; nt < 4; ++nt) {
    qv[nt] += __shfl_xor(qv[nt], 16, 64);
    qv[nt] += __shfl_xor(qv[nt], 32, 64);
  }
  int half = wm >> 6;
  if (q == 0) {
    #pragma unroll
    for (int nt = 0; nt < 4; ++nt) qld[half][wn + nt * 16 + r] = qv[nt];
  }
  __syncthreads();
  float* qarr = set ? a.qneg : a.qpos;
  if (tid < 128) qarr[cb * 128 + tid] = qld[0][tid] + qld[1][tid];
  if (set == 0) {
    int which = tid >> 7, sl = tid & 127;
    const float* Sv = &Sl[which * 128];
    float d = 0.f;
    #pragma unroll
    for (int fb = 0; fb < 16; ++fb) {
      const u16* pv = &T1[sl * LDP + fb * 8];
      #pragma unroll
      for (int j = 0; j < 8; ++j) d += Sv[fb * 8 + j] * bf2f(pv[j]);
    }
    (which ? a.sdneg : a.sdpos)[cb * 128 + sl] = d;
  }
}

// ===== kernel 4 (R1-proven): per-sample terms + MSE reduce + final combine =====
__global__ __launch_bounds__(256) void final_k(Args a) {
  int tid = threadIdx.x;
  int wave = tid >> 6, lane = tid & 63;
  float lg = 0.f, sm = 0.f;
  for (int col = tid; col < 8192; col += 256) {
    bool isp = col < NPOS;
    bool isn = (col >= 4096) && (col < 4096 + NPOS);
    if (isp || isn) {
      float qp = a.qpos[col], qn = a.qneg[col];
      float c = 1.0f / sqrtf(qp + qn);
      float qo  = isp ? qn : qp;
      float sdo = isp ? a.sdneg[col] : a.sdpos[col];
      float sds = isp ? a.sdpos[col] : a.sdneg[col];
      float denom = 4000.0f + c * sdo + 0.5f * c * c * qo;
      lg += logf(denom);
      sm += c * (sds - 1.0f);
    }
  }
  float ms = a.msepart[tid] + a.msepart[tid + 256];
  #pragma unroll
  for (int o = 1; o < 64; o <<= 1) {
    lg += __shfl_xor(lg, o, 64);
    sm += __shfl_xor(sm, o, 64);
    ms += __shfl_xor(ms, o, 64);
  }
  __shared__ float redf[12];
  if (lane == 0) { redf[wave] = lg; redf[4 + wave] = sm; redf[8 + wave] = ms; }
  __syncthreads();
  if (tid == 0) {
    float lgs = redf[0] + redf[1] + redf[2] + redf[3];
    float sms = redf[4] + redf[5] + redf[6] + redf[7];
    float mss = redf[8] + redf[9] + redf[10] + redf[11];
    a.out[0] = lgs - sms * (1.0f / 8000.0f) + 0.5f * (mss * (1.0f / (float)MSE_N));
  }
}

extern "C" void kernel_launch(void* const* d_in, const int* in_sizes, int n_in,
                              void* d_out, int out_size, void* d_ws, size_t ws_size,
                              hipStream_t stream) {
  char* ws = (char*)d_ws;
  Args args;
  args.Zs  = (const float*)d_in[0];
  args.pos = (const int*)d_in[1];
  args.neg = (const int*)d_in[2];
  args.fd  = (const float4*)d_in[3];
  args.idf = (const float4*)d_in[4];
  args.out = (float*)d_out;

  args.Pc      = (u16*)(ws + 0);            // 2,228,224 B
  args.Prow    = (u16*)(ws + 2228224);      // -> 4,456,448
  args.Gb      = (u16*)(ws + 4456448);      //    69,632 -> 4,526,080
  args.S       = (float*)(ws + 4526080);    //     1,024 -> 4,527,104
  args.qpos    = (float*)(ws + 4527104);    //    32,768 -> 4,559,872
  args.qneg    = (float*)(ws + 4559872);    //    32,768 -> 4,592,640
  args.sdpos   = (float*)(ws + 4592640);    //    32,768 -> 4,625,408
  args.sdneg   = (float*)(ws + 4625408);    //    32,768 -> 4,658,176
  args.msepart = (float*)(ws + 4658176);    //     2,048 -> 4,660,224

  prep_k<<<GATHER_B + MSE_B + 2, 256, 0, stream>>>(args);
  gsyrk_k<<<128, 256, 0, stream>>>(args);
  quad_k<<<128, 256, 0, stream>>>(args);
  final_k<<<1, 256, 0, stream>>>(args);
}

// Round 7
// 127.992 us; speedup vs baseline: 1.5512x; 1.0304x over previous
//
#include <hip/hip_runtime.h>
#include <hip/hip_bf16.h>
#include <math.h>

typedef unsigned short u16;
typedef float  f32x4  __attribute__((ext_vector_type(4)));
typedef __bf16 bf16x8 __attribute__((ext_vector_type(8)));

#define NPOS   4000
#define LDP    136       // padded bf16 row stride
#define TILE_CH 2176     // 128*136*2/16 16-byte chunks per 128-row tile
#define MSE_N  4194304
#define GATHER_B 256
#define MSE_B    512
#define TLD    132       // f32 voxel-tile row stride (pad, keeps 16B align)

__device__ __forceinline__ void load_lds16(const void* g, void* l) {
  __builtin_amdgcn_global_load_lds(
      (const __attribute__((address_space(1))) unsigned int*)g,
      (__attribute__((address_space(3))) unsigned int*)l, 16, 0, 0);
}

__device__ __forceinline__ float bf2f(u16 h) {
  unsigned u = ((unsigned)h) << 16;
  return __builtin_bit_cast(float, u);
}

struct Args {
  const float* Zs; const int* pos; const int* neg;
  const float4* fd; const float4* idf;
  u16* Pc; u16* Prow; float* Gpart; float* Spart; u16* Gb; float* S;
  float* qpos; float* qneg; float* sdpos; float* sdneg;
  float* msepart; float* out;
};

// ===== kernel 1: coalesced inverted gather + MSE partials + Pc pad zero =====
__global__ __launch_bounds__(256) void prep_k(Args a) {
  __shared__ __align__(16) float tile[128 * TLD];   // 67,584 B
  __shared__ int mlist[1024];
  __shared__ int mcnt;
  int blk = blockIdx.x, tid = threadIdx.x;
  int wave = tid >> 6, lane = tid & 63;
  if (blk < GATHER_B) {
    int v0 = blk << 7;
    if (tid == 0) mcnt = 0;
    __syncthreads();
    // stage Zs[:, v0:v0+128] coalesced (float4)
    {
      int rq = tid >> 5;              // 0..7
      int c4 = (tid & 31) << 2;       // 0,4,...,124
      #pragma unroll
      for (int p = 0; p < 16; ++p) {
        int f = p * 8 + rq;
        float4 v = *(const float4*)(a.Zs + ((size_t)f << 15) + v0 + c4);
        *(float4*)&tile[f * TLD + c4] = v;
      }
    }
    // scan indices, build match list (col<<7 | local voxel)
    for (int k = 0; k < 4000; k += 256) {
      int i = k + tid;
      if (i < 4000) {
        unsigned dp = (unsigned)(a.pos[i] - v0);
        if (dp < 128u) { int m = atomicAdd(&mcnt, 1); mlist[m] = (i << 7) | dp; }
        unsigned dn = (unsigned)(a.neg[i] - v0);
        if (dn < 128u) { int m = atomicAdd(&mcnt, 1); mlist[m] = ((4096 + i) << 7) | dn; }
      }
    }
    __syncthreads();
    int nm = mcnt;
    for (int m = wave; m < nm; m += 4) {
      int e = mlist[m];
      int col = e >> 7, lv = e & 127;
      float x0 = tile[lane * TLD + lv];
      float x1 = tile[(lane + 64) * TLD + lv];
      float s = x0 * x0 + x1 * x1;
      #pragma unroll
      for (int o = 1; o < 64; o <<= 1) s += __shfl_xor(s, o, 64);
      float inv = 1.0f / fmaxf(sqrtf(s), 1e-12f);
      __hip_bfloat16 h0 = __float2bfloat16(x0 * inv);
      __hip_bfloat16 h1 = __float2bfloat16(x1 * inv);
      u16 b0 = *(u16*)&h0, b1 = *(u16*)&h1;
      a.Prow[(size_t)col * LDP + lane]      = b0;
      a.Prow[(size_t)col * LDP + lane + 64] = b1;
      size_t cbase = (size_t)(col >> 7) * (128 * LDP) + (col & 127);
      a.Pc[cbase + (size_t)lane * LDP]        = b0;
      a.Pc[cbase + (size_t)(lane + 64) * LDP] = b1;
    }
  } else if (blk < GATHER_B + MSE_B) {
    int b = blk - GATHER_B;
    float ms = 0.f;
    for (int idx = b * 256 + tid; idx < MSE_N / 4; idx += MSE_B * 256) {
      float4 u = a.fd[idx], w = a.idf[idx];
      float dx = u.x - w.x, dy = u.y - w.y, dz = u.z - w.z, dv = u.w - w.w;
      ms += dx * dx + dy * dy + dz * dz + dv * dv;
    }
    #pragma unroll
    for (int o = 1; o < 64; o <<= 1) ms += __shfl_xor(ms, o, 64);
    __shared__ float red[4];
    if (lane == 0) red[wave] = ms;
    __syncthreads();
    if (tid == 0) a.msepart[b] = red[0] + red[1] + red[2] + red[3];
  } else {
    // zero invalid Pc sample columns (chunk 31 & 63, cols 32..127)
    int ch = (blk == GATHER_B + MSE_B) ? 31 : 63;
    for (int e = tid; e < 128 * 96; e += 256) {
      int f = e / 96, c = 32 + e % 96;
      a.Pc[(size_t)ch * (128 * LDP) + (size_t)f * LDP + c] = 0;
    }
  }
}

// ===== kernel 2: SYRK partials, 64 blocks (1 tile each), NO atomics =====
__global__ __launch_bounds__(256) void syrk_k(Args a) {
  __shared__ __align__(16) u16 T0[128 * LDP];
  int blk = blockIdx.x, tid = threadIdx.x;     // 64 blocks: b<32 pos, b>=32 neg
  int wave = tid >> 6, lane = tid & 63;
  int wm = (wave >> 1) << 6, wn = (wave & 1) << 6;
  int r = lane & 15, q = lane >> 4;
  f32x4 acc[4][4];
  #pragma unroll
  for (int x = 0; x < 4; ++x)
    #pragma unroll
    for (int y = 0; y < 4; ++y) {
      acc[x][y][0] = 0.f; acc[x][y][1] = 0.f; acc[x][y][2] = 0.f; acc[x][y][3] = 0.f;
    }
  const u16* g = a.Pc + (size_t)blk * (128 * LDP);
  #pragma unroll
  for (int k = 0; k < 9; ++k) {
    int cc = k * 256 + tid;
    if (cc < TILE_CH) load_lds16(g + cc * 8, &T0[cc * 8]);
  }
  __syncthreads();
  #pragma unroll
  for (int kk = 0; kk < 4; ++kk) {
    int k0 = kk * 32 + q * 8;
    bf16x8 af[4], bfr[4];
    #pragma unroll
    for (int t = 0; t < 4; ++t) {
      af[t]  = *(const bf16x8*)&T0[(wm + t * 16 + r) * LDP + k0];
      bfr[t] = *(const bf16x8*)&T0[(wn + t * 16 + r) * LDP + k0];
    }
    #pragma unroll
    for (int mt = 0; mt < 4; ++mt)
      #pragma unroll
      for (int nt = 0; nt < 4; ++nt)
        acc[mt][nt] = __builtin_amdgcn_mfma_f32_16x16x32_bf16(
            af[mt], bfr[nt], acc[mt][nt], 0, 0, 0);
  }
  // per-tile column (feature) sums -> S partials
  {
    int sf = tid >> 1, sh = tid & 1;
    float ssum = 0.f;
    const u16* base = &T0[sf * LDP + sh * 64];
    #pragma unroll
    for (int vb = 0; vb < 8; ++vb) {
      bf16x8 v = *(const bf16x8*)&base[vb * 8];
      #pragma unroll
      for (int j = 0; j < 8; ++j) ssum += (float)v[j];
    }
    ssum += __shfl_xor(ssum, 1, 64);
    if (sh == 0) a.Spart[blk * 128 + sf] = ssum;
  }
  // plain coalesced partial store (no atomics)
  float* Gp = a.Gpart + (size_t)blk * 16384;
  #pragma unroll
  for (int mt = 0; mt < 4; ++mt)
    #pragma unroll
    for (int nt = 0; nt < 4; ++nt)
      #pragma unroll
      for (int reg = 0; reg < 4; ++reg) {
        int ar = wm + mt * 16 + q * 4 + reg;
        int bc = wn + nt * 16 + r;
        Gp[ar * 128 + bc] = acc[mt][nt][reg];
      }
}

// ===== kernel 2b: reduce partials -> G (bf16, padded) + S =====
__global__ __launch_bounds__(256) void reduce_k(Args a) {
  int blk = blockIdx.x, tid = threadIdx.x;
  if (blk < 64) {
    int set = blk >> 5, f0 = (blk & 31) * 4;
    #pragma unroll
    for (int j = 0; j < 2; ++j) {
      int o = j * 256 + tid;                 // 0..511
      int row = f0 + (o >> 7), col = o & 127;
      const float* src = a.Gpart + (size_t)set * 32 * 16384 + row * 128 + col;
      float s = 0.f;
      #pragma unroll
      for (int ch = 0; ch < 32; ++ch) s += src[(size_t)ch * 16384];
      __hip_bfloat16 h = __float2bfloat16(s);
      a.Gb[(size_t)set * (128 * LDP) + row * LDP + col] = *(u16*)&h;
    }
  } else {
    int set = tid >> 7, f = tid & 127;
    const float* sp = a.Spart + (size_t)set * 32 * 128 + f;
    float s = 0.f;
    #pragma unroll
    for (int ch = 0; ch < 32; ++ch) s += sp[ch * 128];
    a.S[tid] = s;
  }
}

// ===== kernel 3: quadratic forms q_set[i] = p_i^T G_set p_i + S-dots =====
__global__ __launch_bounds__(256) void quad_k(Args a) {
  __shared__ __align__(16) u16 T0[128 * LDP];   // G in bf16
  __shared__ __align__(16) u16 T1[128 * LDP];   // P tile
  __shared__ float Sl[256];
  __shared__ float qld[2][128];
  int cb = blockIdx.x & 63, set = blockIdx.x >> 6, tid = threadIdx.x;
  Sl[tid] = a.S[tid];
  const u16* gP = a.Prow + (size_t)cb * (128 * LDP);
  #pragma unroll
  for (int k = 0; k < 9; ++k) {
    int cc = k * 256 + tid;
    if (cc < TILE_CH) load_lds16(gP + cc * 8, &T1[cc * 8]);
  }
  const u16* gG = a.Gb + (size_t)set * (128 * LDP);
  #pragma unroll
  for (int k = 0; k < 9; ++k) {
    int cc = k * 256 + tid;
    if (cc < TILE_CH) load_lds16(gG + cc * 8, &T0[cc * 8]);
  }
  __syncthreads();
  int wave = tid >> 6, lane = tid & 63;
  int wm = (wave >> 1) << 6, wn = (wave & 1) << 6;
  int r = lane & 15, q = lane >> 4;
  f32x4 acc[4][4];
  #pragma unroll
  for (int x = 0; x < 4; ++x)
    #pragma unroll
    for (int y = 0; y < 4; ++y) {
      acc[x][y][0] = 0.f; acc[x][y][1] = 0.f; acc[x][y][2] = 0.f; acc[x][y][3] = 0.f;
    }
  #pragma unroll
  for (int kk = 0; kk < 4; ++kk) {
    int k0 = kk * 32 + q * 8;
    bf16x8 af[4], bfr[4];
    #pragma unroll
    for (int t = 0; t < 4; ++t) {
      af[t]  = *(const bf16x8*)&T0[(wm + t * 16 + r) * LDP + k0];
      bfr[t] = *(const bf16x8*)&T1[(wn + t * 16 + r) * LDP + k0];
    }
    #pragma unroll
    for (int mt = 0; mt < 4; ++mt)
      #pragma unroll
      for (int nt = 0; nt < 4; ++nt)
        acc[mt][nt] = __builtin_amdgcn_mfma_f32_16x16x32_bf16(
            af[mt], bfr[nt], acc[mt][nt], 0, 0, 0);
  }
  float qv[4] = {0.f, 0.f, 0.f, 0.f};
  #pragma unroll
  for (int nt = 0; nt < 4; ++nt) {
    int il = wn + nt * 16 + r;
    #pragma unroll
    for (int mt = 0; mt < 4; ++mt) {
      const u16* pp = &T1[il * LDP + wm + mt * 16 + q * 4];
      #pragma unroll
      for (int reg = 0; reg < 4; ++reg)
        qv[nt] += acc[mt][nt][reg] * bf2f(pp[reg]);
    }
  }
  #pragma unroll
  for (int nt = 0; nt < 4; ++nt) {
    qv[nt] += __shfl_xor(qv[nt], 16, 64);
    qv[nt] += __shfl_xor(qv[nt], 32, 64);
  }
  int half = wm >> 6;
  if (q == 0) {
    #pragma unroll
    for (int nt = 0; nt < 4; ++nt) qld[half][wn + nt * 16 + r] = qv[nt];
  }
  __syncthreads();
  float* qarr = set ? a.qneg : a.qpos;
  if (tid < 128) qarr[cb * 128 + tid] = qld[0][tid] + qld[1][tid];
  if (set == 0) {
    int which = tid >> 7, sl = tid & 127;
    const float* Sv = &Sl[which * 128];
    float d = 0.f;
    #pragma unroll
    for (int fb = 0; fb < 16; ++fb) {
      const u16* pv = &T1[sl * LDP + fb * 8];
      #pragma unroll
      for (int j = 0; j < 8; ++j) d += Sv[fb * 8 + j] * bf2f(pv[j]);
    }
    (which ? a.sdneg : a.sdpos)[cb * 128 + sl] = d;
  }
}

// ===== kernel 4: per-sample terms + MSE reduce + final combine =====
__global__ __launch_bounds__(256) void final_k(Args a) {
  int tid = threadIdx.x;
  int wave = tid >> 6, lane = tid & 63;
  float lg = 0.f, sm = 0.f;
  for (int col = tid; col < 8192; col += 256) {
    bool isp = col < NPOS;
    bool isn = (col >= 4096) && (col < 4096 + NPOS);
    if (isp || isn) {
      float qp = a.qpos[col], qn = a.qneg[col];
      float c = 1.0f / sqrtf(qp + qn);
      float qo  = isp ? qn : qp;
      float sdo = isp ? a.sdneg[col] : a.sdpos[col];
      float sds = isp ? a.sdpos[col] : a.sdneg[col];
      float denom = 4000.0f + c * sdo + 0.5f * c * c * qo;
      lg += logf(denom);
      sm += c * (sds - 1.0f);
    }
  }
  float ms = a.msepart[tid] + a.msepart[tid + 256];
  #pragma unroll
  for (int o = 1; o < 64; o <<= 1) {
    lg += __shfl_xor(lg, o, 64);
    sm += __shfl_xor(sm, o, 64);
    ms += __shfl_xor(ms, o, 64);
  }
  __shared__ float redf[12];
  if (lane == 0) { redf[wave] = lg; redf[4 + wave] = sm; redf[8 + wave] = ms; }
  __syncthreads();
  if (tid == 0) {
    float lgs = redf[0] + redf[1] + redf[2] + redf[3];
    float sms = redf[4] + redf[5] + redf[6] + redf[7];
    float mss = redf[8] + redf[9] + redf[10] + redf[11];
    a.out[0] = lgs - sms * (1.0f / 8000.0f) + 0.5f * (mss * (1.0f / (float)MSE_N));
  }
}

extern "C" void kernel_launch(void* const* d_in, const int* in_sizes, int n_in,
                              void* d_out, int out_size, void* d_ws, size_t ws_size,
                              hipStream_t stream) {
  char* ws = (char*)d_ws;
  Args args;
  args.Zs  = (const float*)d_in[0];
  args.pos = (const int*)d_in[1];
  args.neg = (const int*)d_in[2];
  args.fd  = (const float4*)d_in[3];
  args.idf = (const float4*)d_in[4];
  args.out = (float*)d_out;

  args.Pc      = (u16*)(ws + 0);            // 2,228,224 B
  args.Prow    = (u16*)(ws + 2228224);      // -> 4,456,448
  args.Gpart   = (float*)(ws + 4456448);    // 4,194,304 -> 8,650,752
  args.Spart   = (float*)(ws + 8650752);    //    32,768 -> 8,683,520
  args.Gb      = (u16*)(ws + 8683520);      //    69,632 -> 8,753,152
  args.S       = (float*)(ws + 8753152);    //     1,024 -> 8,754,176
  args.qpos    = (float*)(ws + 8754176);    //    32,768 -> 8,786,944
  args.qneg    = (float*)(ws + 8786944);    //    32,768 -> 8,819,712
  args.sdpos   = (float*)(ws + 8819712);    //    32,768 -> 8,852,480
  args.sdneg   = (float*)(ws + 8852480);    //    32,768 -> 8,885,248
  args.msepart = (float*)(ws + 8885248);    //     2,048 -> 8,887,296

  prep_k<<<GATHER_B + MSE_B + 2, 256, 0, stream>>>(args);
  syrk_k<<<64, 256, 0, stream>>>(args);
  reduce_k<<<65, 256, 0, stream>>>(args);
  quad_k<<<128, 256, 0, stream>>>(args);
  final_k<<<1, 256, 0, stream>>>(args);
}